// Round 1
// baseline (196.820 us; speedup 1.0000x reference)
//
#include <hip/hip_runtime.h>
#include <math.h>

#define ATTN_SCALE 0.125f
#define NORM_EPS   1e-12f

// One wave (64 lanes) per query row.
// Row r: q[r,64], key[r,32,64], val[r,32,64], mask[r,32], sv[r,64] -> out[r,64]
// Lane layout: lane = g*16 + sub  (g = 0..3, sub = 0..15)
//   float4 chunk c = i*64 + lane  covers key slot k = i*4 + g, dims d0 = sub*4 .. +3
__global__ __launch_bounds__(256) void attn_core_kernel(
    const float* __restrict__ q,     // (R, 64)
    const float* __restrict__ key,   // (R, 32, 64)
    const float* __restrict__ val,   // (R, 32, 64)
    const int*   __restrict__ mask,  // (R, 32)
    const float* __restrict__ sv,    // (R, 64)
    float*       __restrict__ out,   // (R, 64)
    int nrows)
{
    const int wave = (int)((blockIdx.x * blockDim.x + threadIdx.x) >> 6);
    if (wave >= nrows) return;
    const int lane = threadIdx.x & 63;
    const int g    = lane >> 4;    // key-group 0..3
    const int sub  = lane & 15;    // d-chunk 0..15
    const int d0   = sub * 4;

    const size_t rkv = (size_t)wave * 2048;   // 32*64
    const size_t rq  = (size_t)wave * 64;
    const size_t rm  = (size_t)wave * 32;

    // ---- issue all loads up front (independent -> deep MLP) ----
    const float4 q4 = *(const float4*)(q  + rq + d0);
    const float4 s4 = *(const float4*)(sv + rq + d0);

    float4 kt[8], vt[8];
#pragma unroll
    for (int i = 0; i < 8; ++i)
        kt[i] = *(const float4*)(key + rkv + (size_t)(i * 64 + lane) * 4);
#pragma unroll
    for (int i = 0; i < 8; ++i)
        vt[i] = *(const float4*)(val + rkv + (size_t)(i * 64 + lane) * 4);

    int mk[8];
#pragma unroll
    for (int i = 0; i < 8; ++i)
        mk[i] = mask[rm + i * 4 + g];      // uniform within 16-lane group (L1 broadcast)

    // ---- scores: dot(q, key[k]) for k = i*4 + g ----
    float sc[8];
#pragma unroll
    for (int i = 0; i < 8; ++i) {
        float p = q4.x * kt[i].x + q4.y * kt[i].y + q4.z * kt[i].z + q4.w * kt[i].w;
        p += __shfl_xor(p, 1);
        p += __shfl_xor(p, 2);
        p += __shfl_xor(p, 4);
        p += __shfl_xor(p, 8);             // full 64-dim dot, replicated in 16-lane group
        sc[i] = mk[i] ? p * ATTN_SCALE : -3.0e38f;
    }

    // ---- softmax over 32 slots (8 local regs x 4 groups) ----
    float m = sc[0];
#pragma unroll
    for (int i = 1; i < 8; ++i) m = fmaxf(m, sc[i]);
    m = fmaxf(m, __shfl_xor(m, 16));
    m = fmaxf(m, __shfl_xor(m, 32));

    float e[8], sum = 0.f;
#pragma unroll
    for (int i = 0; i < 8; ++i) { e[i] = __expf(sc[i] - m); sum += e[i]; }
    sum += __shfl_xor(sum, 16);
    sum += __shfl_xor(sum, 32);
    const float inv = 1.0f / sum;

    // ---- PV: out[d0..d0+3] partial over this lane's 8 k's ----
    float4 o = make_float4(0.f, 0.f, 0.f, 0.f);
#pragma unroll
    for (int i = 0; i < 8; ++i) {
        const float a = e[i] * inv;
        o.x += a * vt[i].x; o.y += a * vt[i].y; o.z += a * vt[i].z; o.w += a * vt[i].w;
    }
    // reduce across the 4 key-groups
#pragma unroll
    for (int s = 16; s <= 32; s <<= 1) {
        o.x += __shfl_xor(o.x, s);
        o.y += __shfl_xor(o.y, s);
        o.z += __shfl_xor(o.z, s);
        o.w += __shfl_xor(o.w, s);
    }
    // o now holds out[d0..d0+3] replicated in all 4 groups

    // ---- epilogue: remove component along normalized self_value ----
    float ns = s4.x * s4.x + s4.y * s4.y + s4.z * s4.z + s4.w * s4.w;
    ns += __shfl_xor(ns, 1);
    ns += __shfl_xor(ns, 2);
    ns += __shfl_xor(ns, 4);
    ns += __shfl_xor(ns, 8);               // ||sv||^2 over all 64 dims
    const float denom = fmaxf(sqrtf(ns), NORM_EPS);
    const float rinv = 1.0f / denom;
    const float ux = s4.x * rinv, uy = s4.y * rinv, uz = s4.z * rinv, uw = s4.w * rinv;

    float dt = o.x * ux + o.y * uy + o.z * uz + o.w * uw;
    dt += __shfl_xor(dt, 1);
    dt += __shfl_xor(dt, 2);
    dt += __shfl_xor(dt, 4);
    dt += __shfl_xor(dt, 8);               // dot(out, unit) over all 64 dims

    o.x -= dt * ux; o.y -= dt * uy; o.z -= dt * uz; o.w -= dt * uw;

    if (g == 0)
        *(float4*)(out + rq + d0) = o;     // 16 lanes x 16 B = 256 B coalesced
}

extern "C" void kernel_launch(void* const* d_in, const int* in_sizes, int n_in,
                              void* d_out, int out_size, void* d_ws, size_t ws_size,
                              hipStream_t stream) {
    const float* q    = (const float*)d_in[0];
    const float* key  = (const float*)d_in[1];
    const float* val  = (const float*)d_in[2];
    const int*   mask = (const int*)  d_in[3];
    const float* sv   = (const float*)d_in[4];
    float*       out  = (float*)d_out;

    const int nrows = in_sizes[0] / 64;          // B*H*T = 65536
    const int waves_per_block = 4;               // 256 threads
    const int blocks = (nrows + waves_per_block - 1) / waves_per_block;
    attn_core_kernel<<<blocks, 256, 0, stream>>>(q, key, val, mask, sv, out, nrows);
}

// Round 2
// 174.078 us; speedup vs baseline: 1.1306x; 1.1306x over previous
//
#include <hip/hip_runtime.h>
#include <math.h>

#define ATTN_SCALE 0.125f
#define NORM_EPS   1e-12f

// One wave (64 lanes) per query row.
// Row r: q[r,64], key[r,32,64], val[r,32,64], mask[r,32], sv[r,64] -> out[r,64]
// Lane layout: lane = g*16 + sub  (g = 0..3, sub = 0..15)
//   float4 chunk c = i*64 + lane  covers key slot k = i*4 + g, dims d0 = sub*4 .. +3
// key/value/out are streamed exactly once -> nontemporal to avoid L2/LLC pollution.

__device__ __forceinline__ float4 nt_load4(const float* p) {
    const float* __restrict__ pp = p;
    float4 r;
    r.x = __builtin_nontemporal_load(pp + 0);
    r.y = __builtin_nontemporal_load(pp + 1);
    r.z = __builtin_nontemporal_load(pp + 2);
    r.w = __builtin_nontemporal_load(pp + 3);
    return r;
}

__global__ __launch_bounds__(256) void attn_core_kernel(
    const float* __restrict__ q,     // (R, 64)
    const float* __restrict__ key,   // (R, 32, 64)
    const float* __restrict__ val,   // (R, 32, 64)
    const int*   __restrict__ mask,  // (R, 32)
    const float* __restrict__ sv,    // (R, 64)
    float*       __restrict__ out,   // (R, 64)
    int nrows)
{
    const int wave = (int)((blockIdx.x * blockDim.x + threadIdx.x) >> 6);
    if (wave >= nrows) return;
    const int lane = threadIdx.x & 63;
    const int g    = lane >> 4;    // key-group 0..3
    const int sub  = lane & 15;    // d-chunk 0..15
    const int d0   = sub * 4;

    const size_t rkv = (size_t)wave * 2048;   // 32*64
    const size_t rq  = (size_t)wave * 64;
    const size_t rm  = (size_t)wave * 32;

    // ---- issue all loads up front (independent -> deep MLP) ----
    const float4 q4 = *(const float4*)(q  + rq + d0);
    const float4 s4 = *(const float4*)(sv + rq + d0);

    float4 kt[8], vt[8];
#pragma unroll
    for (int i = 0; i < 8; ++i)
        kt[i] = nt_load4(key + rkv + (size_t)(i * 64 + lane) * 4);
#pragma unroll
    for (int i = 0; i < 8; ++i)
        vt[i] = nt_load4(val + rkv + (size_t)(i * 64 + lane) * 4);

    int mk[8];
#pragma unroll
    for (int i = 0; i < 8; ++i)
        mk[i] = mask[rm + i * 4 + g];      // uniform within 16-lane group (L1 broadcast)

    // ---- scores: dot(q, key[k]) for k = i*4 + g ----
    float sc[8];
#pragma unroll
    for (int i = 0; i < 8; ++i) {
        float p = q4.x * kt[i].x + q4.y * kt[i].y + q4.z * kt[i].z + q4.w * kt[i].w;
        p += __shfl_xor(p, 1);
        p += __shfl_xor(p, 2);
        p += __shfl_xor(p, 4);
        p += __shfl_xor(p, 8);             // full 64-dim dot, replicated in 16-lane group
        sc[i] = mk[i] ? p * ATTN_SCALE : -3.0e38f;
    }

    // ---- softmax over 32 slots (8 local regs x 4 groups) ----
    float m = sc[0];
#pragma unroll
    for (int i = 1; i < 8; ++i) m = fmaxf(m, sc[i]);
    m = fmaxf(m, __shfl_xor(m, 16));
    m = fmaxf(m, __shfl_xor(m, 32));

    float e[8], sum = 0.f;
#pragma unroll
    for (int i = 0; i < 8; ++i) { e[i] = __expf(sc[i] - m); sum += e[i]; }
    sum += __shfl_xor(sum, 16);
    sum += __shfl_xor(sum, 32);
    const float inv = 1.0f / sum;

    // ---- PV: out[d0..d0+3] partial over this lane's 8 k's ----
    float4 o = make_float4(0.f, 0.f, 0.f, 0.f);
#pragma unroll
    for (int i = 0; i < 8; ++i) {
        const float a = e[i] * inv;
        o.x += a * vt[i].x; o.y += a * vt[i].y; o.z += a * vt[i].z; o.w += a * vt[i].w;
    }
    // reduce across the 4 key-groups
#pragma unroll
    for (int s = 16; s <= 32; s <<= 1) {
        o.x += __shfl_xor(o.x, s);
        o.y += __shfl_xor(o.y, s);
        o.z += __shfl_xor(o.z, s);
        o.w += __shfl_xor(o.w, s);
    }
    // o now holds out[d0..d0+3] replicated in all 4 groups

    // ---- epilogue: remove component along normalized self_value ----
    float ns = s4.x * s4.x + s4.y * s4.y + s4.z * s4.z + s4.w * s4.w;
    ns += __shfl_xor(ns, 1);
    ns += __shfl_xor(ns, 2);
    ns += __shfl_xor(ns, 4);
    ns += __shfl_xor(ns, 8);               // ||sv||^2 over all 64 dims
    const float denom = fmaxf(sqrtf(ns), NORM_EPS);
    const float rinv = 1.0f / denom;
    const float ux = s4.x * rinv, uy = s4.y * rinv, uz = s4.z * rinv, uw = s4.w * rinv;

    float dt = o.x * ux + o.y * uy + o.z * uz + o.w * uw;
    dt += __shfl_xor(dt, 1);
    dt += __shfl_xor(dt, 2);
    dt += __shfl_xor(dt, 4);
    dt += __shfl_xor(dt, 8);               // dot(out, unit) over all 64 dims

    o.x -= dt * ux; o.y -= dt * uy; o.z -= dt * uz; o.w -= dt * uw;

    if (g == 0) {
        float* __restrict__ po = out + rq + d0;
        __builtin_nontemporal_store(o.x, po + 0);
        __builtin_nontemporal_store(o.y, po + 1);
        __builtin_nontemporal_store(o.z, po + 2);
        __builtin_nontemporal_store(o.w, po + 3);
    }
}

extern "C" void kernel_launch(void* const* d_in, const int* in_sizes, int n_in,
                              void* d_out, int out_size, void* d_ws, size_t ws_size,
                              hipStream_t stream) {
    const float* q    = (const float*)d_in[0];
    const float* key  = (const float*)d_in[1];
    const float* val  = (const float*)d_in[2];
    const int*   mask = (const int*)  d_in[3];
    const float* sv   = (const float*)d_in[4];
    float*       out  = (float*)d_out;

    const int nrows = in_sizes[0] / 64;          // B*H*T = 65536
    const int waves_per_block = 4;               // 256 threads
    const int blocks = (nrows + waves_per_block - 1) / waves_per_block;
    attn_core_kernel<<<blocks, 256, 0, stream>>>(q, key, val, mask, sv, out, nrows);
}